// Round 1
// baseline (1224.839 us; speedup 1.0000x reference)
//
#include <hip/hip_runtime.h>
#include <hip/hip_bf16.h>

typedef __bf16 bf16x8 __attribute__((ext_vector_type(8)));
typedef __bf16 bf16x4 __attribute__((ext_vector_type(4)));
typedef float  f32x4  __attribute__((ext_vector_type(4)));
typedef float  f32x16 __attribute__((ext_vector_type(16)));

#define NPOS 49
#define NHEADS 8
#define SCALE_F 0.17677669529663687f

// LDS layout (bytes)
#define XWT_PITCH 264      // bf16 elements per row of xwT / aoT
#define QK_PITCH  520      // bf16 elements per row of q|k buffer
#define VT_PITCH  72       // bf16 elements per row of v^T buffer
#define AOT_PITCH 264

#define XWT_OFF   0        // bf16 [64][264]; later: P regions, 4 waves x 8192 B
#define QK_OFF    33792    // bf16 [64][520] (o in [0,512)); later: aoT [64][264]
#define VT_OFF    100352   // bf16 [256][72]
#define BIAS_OFF  137216   // float [2401]
#define BO_OFF    146820   // float [256]
#define LDS_BYTES 147856

static __device__ __forceinline__ f32x16 zero16() {
  f32x16 z;
#pragma unroll
  for (int i = 0; i < 16; ++i) z[i] = 0.f;
  return z;
}

__global__ void prep_kernel(const float* __restrict__ Wq, const float* __restrict__ Wkv,
                            const float* __restrict__ Wo, const float* __restrict__ pos,
                            const int* __restrict__ rel, __bf16* __restrict__ wqkv,
                            __bf16* __restrict__ wo, float* __restrict__ bias) {
  int idx = blockIdx.x * 256 + threadIdx.x;
  if (idx < 256 * 256) wqkv[idx] = (__bf16)Wq[idx];             // q rows 0..255
  if (idx < 512 * 256) wqkv[256 * 256 + idx] = (__bf16)Wkv[idx]; // k rows 256..511, v rows 512..767
  if (idx < 256 * 256) wo[idx] = (__bf16)Wo[idx];
  if (idx < 49 * 49) bias[idx] = pos[rel[idx * 2] * 13 + rel[idx * 2 + 1]];
}

__global__ __launch_bounds__(256, 1) void attn_kernel(
    const float* __restrict__ x, const __bf16* __restrict__ wqkv,
    const __bf16* __restrict__ wo, const float* __restrict__ bias_g,
    const float* __restrict__ bo_g, float* __restrict__ outg,
    float* __restrict__ attng) {
  extern __shared__ char smem[];
  __bf16* xwT = (__bf16*)(smem + XWT_OFF);
  __bf16* qk  = (__bf16*)(smem + QK_OFF);
  __bf16* vT  = (__bf16*)(smem + VT_OFF);
  __bf16* aoT = (__bf16*)(smem + QK_OFF);
  float* bias_s = (float*)(smem + BIAS_OFF);
  float* bo_s   = (float*)(smem + BO_OFF);

  const int tid = threadIdx.x;
  const int wid = blockIdx.x;
  const int b  = wid >> 8;
  const int i1 = (wid >> 4) & 15;
  const int i2 = wid & 15;
  const int r0 = i1 * 7, c0 = i2 * 7;
  const int wave = tid >> 6, lane = tid & 63;
  const int l31 = lane & 31, g2 = lane >> 5;
  const int c16 = lane & 15, g4 = lane >> 4;

  // ---------------- phase 0: stage x window (bf16, transposed), bias, bo ----------------
  {
    const int n = tid & 63, cb = tid >> 6;
    const int pr = n / 7, pc = n - pr * 7;
    const float* xg = x + (size_t)b * 256 * 12544 + (size_t)(r0 + pr) * 112 + (c0 + pc);
#pragma unroll 8
    for (int it = 0; it < 64; ++it) {
      const int c = it * 4 + cb;
      float v = 0.f;
      if (n < NPOS) v = xg[(size_t)c * 12544];
      xwT[n * XWT_PITCH + c] = (__bf16)v;
    }
    for (int i = tid; i < 2401; i += 256) bias_s[i] = bias_g[i];
    if (tid < 256) bo_s[tid] = bo_g[tid];
  }
  __syncthreads();

  // ---------------- GEMM1: qkv[768][64] = Wqkv[768][256] @ xw[256][64] ----------------
  {
    bf16x8 Bf0[16], Bf1[16];
    const __bf16* Bp = xwT + l31 * XWT_PITCH + g2 * 8;
#pragma unroll
    for (int ks = 0; ks < 16; ++ks) {
      Bf0[ks] = *(const bf16x8*)(Bp + ks * 16);
      Bf1[ks] = *(const bf16x8*)(Bp + 32 * XWT_PITCH + ks * 16);
    }
#pragma unroll 1
    for (int mp = 0; mp < 3; ++mp) {
      const int mt0 = wave * 6 + mp * 2;  // 32-row output tile index (0..23)
      const __bf16* Ap0 = wqkv + (size_t)(mt0 * 32 + l31) * 256 + g2 * 8;
      const __bf16* Ap1 = Ap0 + 32 * 256;
      f32x16 a00 = zero16(), a01 = zero16(), a10 = zero16(), a11 = zero16();
#pragma unroll
      for (int ks = 0; ks < 16; ++ks) {
        bf16x8 A0 = *(const bf16x8*)(Ap0 + ks * 16);
        bf16x8 A1 = *(const bf16x8*)(Ap1 + ks * 16);
        a00 = __builtin_amdgcn_mfma_f32_32x32x16_bf16(A0, Bf0[ks], a00, 0, 0, 0);
        a01 = __builtin_amdgcn_mfma_f32_32x32x16_bf16(A0, Bf1[ks], a01, 0, 0, 0);
        a10 = __builtin_amdgcn_mfma_f32_32x32x16_bf16(A1, Bf0[ks], a10, 0, 0, 0);
        a11 = __builtin_amdgcn_mfma_f32_32x32x16_bf16(A1, Bf1[ks], a11, 0, 0, 0);
      }
#define STORE_QKV(ACC, MT, NT)                                                   \
      {                                                                          \
        const int ob = (MT) * 32;                                                \
        const int n_ = (NT) * 32 + l31;                                          \
        if (ob < 512) {                                                          \
          _Pragma("unroll") for (int rb = 0; rb < 4; ++rb) {                     \
            const int row = ob + rb * 8 + g2 * 4;                                \
            bf16x4 v4;                                                           \
            v4[0] = (__bf16)ACC[rb * 4 + 0]; v4[1] = (__bf16)ACC[rb * 4 + 1];    \
            v4[2] = (__bf16)ACC[rb * 4 + 2]; v4[3] = (__bf16)ACC[rb * 4 + 3];    \
            *(bf16x4*)(qk + n_ * QK_PITCH + row) = v4;                           \
          }                                                                      \
        } else {                                                                 \
          _Pragma("unroll") for (int rg = 0; rg < 16; ++rg) {                    \
            const int row = ob - 512 + (rg & 3) + 8 * (rg >> 2) + 4 * g2;        \
            vT[row * VT_PITCH + n_] = (__bf16)ACC[rg];                           \
          }                                                                      \
        }                                                                        \
      }
      STORE_QKV(a00, mt0, 0)
      STORE_QKV(a01, mt0, 1)
      STORE_QKV(a10, mt0 + 1, 0)
      STORE_QKV(a11, mt0 + 1, 1)
    }
  }
  __syncthreads();

  // ---------------- attention: 2 heads per wave ----------------
  f32x4 pacc[2][4][2];
  float invs[2][4][4];
#pragma unroll
  for (int hh = 0; hh < 2; ++hh) {
    const int h = wave * 2 + hh;
    // QK^T
    bf16x8 qf[4], kf[4];
#pragma unroll
    for (int t = 0; t < 4; ++t) {
      qf[t] = *(const bf16x8*)(qk + (t * 16 + c16) * QK_PITCH + h * 32 + g4 * 8);
      kf[t] = *(const bf16x8*)(qk + (t * 16 + c16) * QK_PITCH + 256 + h * 32 + g4 * 8);
    }
    f32x4 dacc[4][4];
    const f32x4 z4 = {0.f, 0.f, 0.f, 0.f};
#pragma unroll
    for (int mt = 0; mt < 4; ++mt)
#pragma unroll
      for (int nt = 0; nt < 4; ++nt)
        dacc[mt][nt] = __builtin_amdgcn_mfma_f32_16x16x32_bf16(qf[mt], kf[nt], z4, 0, 0, 0);

    // softmax (fp32) + attn output + P (unnormalized, bf16, XOR-swizzled LDS)
    char* Pbase = smem + XWT_OFF + wave * 8192;
#pragma unroll
    for (int mt = 0; mt < 4; ++mt) {
#pragma unroll
      for (int r = 0; r < 4; ++r) {
        const int i = mt * 16 + g4 * 4 + r;
        float v[4];
#pragma unroll
        for (int nt = 0; nt < 4; ++nt) {
          const int j = nt * 16 + c16;
          float val = dacc[mt][nt][r] * SCALE_F;
          if (j < NPOS) {
            if (i < NPOS) val += bias_s[i * 49 + j];
          } else {
            val = -1e30f;
          }
          v[nt] = val;
        }
        float m = fmaxf(fmaxf(v[0], v[1]), fmaxf(v[2], v[3]));
        m = fmaxf(m, __shfl_xor(m, 1)); m = fmaxf(m, __shfl_xor(m, 2));
        m = fmaxf(m, __shfl_xor(m, 4)); m = fmaxf(m, __shfl_xor(m, 8));
        float p[4]; float s = 0.f;
#pragma unroll
        for (int nt = 0; nt < 4; ++nt) { p[nt] = __expf(v[nt] - m); s += p[nt]; }
        s += __shfl_xor(s, 1); s += __shfl_xor(s, 2);
        s += __shfl_xor(s, 4); s += __shfl_xor(s, 8);
        const float inv = 1.f / s;
        invs[hh][mt][r] = inv;
        if (i < NPOS) {
          float* ap = attng + ((size_t)(wid * NHEADS + h) * 49 + i) * 49;
#pragma unroll
          for (int nt = 0; nt < 4; ++nt) {
            const int j = nt * 16 + c16;
            if (j < NPOS) ap[j] = p[nt] * inv;
          }
        }
#pragma unroll
        for (int nt = 0; nt < 4; ++nt) {
          const int j = nt * 16 + c16;
          *(__bf16*)(Pbase + i * 128 + 16 * ((j >> 3) ^ (i & 7)) + 2 * (j & 7)) = (__bf16)p[nt];
        }
      }
    }

    // PV: out_h[i][d] = sum_j P[i][j] * v[j][d]
    bf16x8 vf[2][2];
#pragma unroll
    for (int nt = 0; nt < 2; ++nt)
#pragma unroll
      for (int ks = 0; ks < 2; ++ks)
        vf[nt][ks] = *(const bf16x8*)(vT + (h * 32 + nt * 16 + c16) * VT_PITCH + ks * 32 + g4 * 8);
#pragma unroll
    for (int mt = 0; mt < 4; ++mt) {
      const int i = mt * 16 + c16;
      bf16x8 pa0 = *(const bf16x8*)(Pbase + i * 128 + 16 * ((0 * 4 + g4) ^ (i & 7)));
      bf16x8 pa1 = *(const bf16x8*)(Pbase + i * 128 + 16 * ((1 * 4 + g4) ^ (i & 7)));
#pragma unroll
      for (int nt = 0; nt < 2; ++nt) {
        f32x4 acc = {0.f, 0.f, 0.f, 0.f};
        acc = __builtin_amdgcn_mfma_f32_16x16x32_bf16(pa0, vf[nt][0], acc, 0, 0, 0);
        acc = __builtin_amdgcn_mfma_f32_16x16x32_bf16(pa1, vf[nt][1], acc, 0, 0, 0);
        pacc[hh][mt][nt] = acc;
      }
    }
  }
  __syncthreads();  // all waves done reading qk/vT

  // ---------------- write attn_out^T [n][256] (overlay qk region) ----------------
#pragma unroll
  for (int hh = 0; hh < 2; ++hh) {
    const int h = wave * 2 + hh;
#pragma unroll
    for (int mt = 0; mt < 4; ++mt)
#pragma unroll
      for (int nt = 0; nt < 2; ++nt)
#pragma unroll
        for (int e = 0; e < 4; ++e) {
          const int i = mt * 16 + g4 * 4 + e;
          const int cc = h * 32 + nt * 16 + c16;
          aoT[i * AOT_PITCH + cc] = (__bf16)(pacc[hh][mt][nt][e] * invs[hh][mt][e]);
        }
  }
  __syncthreads();

  // ---------------- GEMM4: out[256][64] = Wo[256][256] @ aoT^T + bo ----------------
  {
    bf16x8 Bf0[16], Bf1[16];
    const __bf16* Bp = aoT + l31 * AOT_PITCH + g2 * 8;
#pragma unroll
    for (int ks = 0; ks < 16; ++ks) {
      Bf0[ks] = *(const bf16x8*)(Bp + ks * 16);
      Bf1[ks] = *(const bf16x8*)(Bp + 32 * AOT_PITCH + ks * 16);
    }
    const __bf16* Ap0 = wo + (size_t)(wave * 64 + l31) * 256 + g2 * 8;
    const __bf16* Ap1 = Ap0 + 32 * 256;
    f32x16 a00 = zero16(), a01 = zero16(), a10 = zero16(), a11 = zero16();
#pragma unroll
    for (int ks = 0; ks < 16; ++ks) {
      bf16x8 A0 = *(const bf16x8*)(Ap0 + ks * 16);
      bf16x8 A1 = *(const bf16x8*)(Ap1 + ks * 16);
      a00 = __builtin_amdgcn_mfma_f32_32x32x16_bf16(A0, Bf0[ks], a00, 0, 0, 0);
      a01 = __builtin_amdgcn_mfma_f32_32x32x16_bf16(A0, Bf1[ks], a01, 0, 0, 0);
      a10 = __builtin_amdgcn_mfma_f32_32x32x16_bf16(A1, Bf0[ks], a10, 0, 0, 0);
      a11 = __builtin_amdgcn_mfma_f32_32x32x16_bf16(A1, Bf1[ks], a11, 0, 0, 0);
    }
    float* og = outg + (size_t)b * 256 * 12544;
#define STORE_OUT(ACC, MT, NT)                                                    \
    {                                                                             \
      const int n_ = (NT) * 32 + l31;                                             \
      if (n_ < NPOS) {                                                            \
        const int pr_ = n_ / 7, pc_ = n_ - pr_ * 7;                               \
        float* orow = og + (size_t)(r0 + pr_) * 112 + (c0 + pc_);                 \
        _Pragma("unroll") for (int rg = 0; rg < 16; ++rg) {                       \
          const int o2 = wave * 64 + (MT) * 32 + (rg & 3) + 8 * (rg >> 2) + 4 * g2; \
          orow[(size_t)o2 * 12544] = ACC[rg] + bo_s[o2];                          \
        }                                                                         \
      }                                                                           \
    }
    STORE_OUT(a00, 0, 0)
    STORE_OUT(a01, 0, 1)
    STORE_OUT(a10, 1, 0)
    STORE_OUT(a11, 1, 1)
  }
}

extern "C" void kernel_launch(void* const* d_in, const int* in_sizes, int n_in,
                              void* d_out, int out_size, void* d_ws, size_t ws_size,
                              hipStream_t stream) {
  const float* x   = (const float*)d_in[0];
  const float* Wq  = (const float*)d_in[1];
  const float* Wkv = (const float*)d_in[2];
  const float* Wo  = (const float*)d_in[3];
  const float* bo  = (const float*)d_in[4];
  const float* pos = (const float*)d_in[5];
  const int*   rel = (const int*)d_in[6];

  float* outg  = (float*)d_out;
  float* attng = outg + (size_t)16 * 256 * 112 * 112;

  __bf16* wqkv = (__bf16*)d_ws;
  __bf16* wo   = wqkv + 768 * 256;
  float*  bias = (float*)(wo + 256 * 256);

  static int shmem_set = 0;
  (void)shmem_set;
  hipFuncSetAttribute((const void*)attn_kernel,
                      hipFuncAttributeMaxDynamicSharedMemorySize, LDS_BYTES);

  prep_kernel<<<dim3(512), dim3(256), 0, stream>>>(Wq, Wkv, Wo, pos, rel, wqkv, wo, bias);
  attn_kernel<<<dim3(4096), dim3(256), LDS_BYTES, stream>>>(x, wqkv, wo, bias, bo, outg, attng);
}

// Round 3
// 733.835 us; speedup vs baseline: 1.6691x; 1.6691x over previous
//
#include <hip/hip_runtime.h>
#include <hip/hip_bf16.h>

typedef __bf16 bf16x8 __attribute__((ext_vector_type(8)));
typedef __bf16 bf16x4 __attribute__((ext_vector_type(4)));
typedef float  f32x4  __attribute__((ext_vector_type(4)));
typedef float  f32x16 __attribute__((ext_vector_type(16)));

#define NPOS 49
#define NHEADS 8
#define SCALE_F 0.17677669529663687f

// ---- LDS layout ----
// 4 per-wave slices of SLICE_B bytes at smem[0..67584):
//   phase0/GEMM1-prologue: smem[0..33792) also holds xwT [64][264] bf16 (waves 0,1 slices)
//   per-wave slice: qk [64 pos][132 dd] bf16 (pitch 264 B; dd ELEMENTS: q=0..63, k=64..127)
//                   vs (transient) at slice+8192: [64 dd][68 pos] bf16 (pitch 136 B)
//                   P  at slice+8192: [64 i][128 B] swizzled bf16
//   epilogue: smem[0..33792) holds aoT [64][264] bf16
#define SLICE_B   16896
#define QK_ROW_B  264
#define VS_OFF    8192
#define VS_ROW_B  136
#define P_OFF     8192
#define XWT_PITCH 264
#define AOT_PITCH 264
#define BIAS_OFF  67584
#define BO_OFF    77188
#define LDS_BYTES 78212

static __device__ __forceinline__ f32x16 zero16() {
  f32x16 z;
#pragma unroll
  for (int i = 0; i < 16; ++i) z[i] = 0.f;
  return z;
}

__global__ void prep_kernel(const float* __restrict__ Wq, const float* __restrict__ Wkv,
                            const float* __restrict__ Wo, const float* __restrict__ pos,
                            const int* __restrict__ rel, __bf16* __restrict__ wqkv,
                            __bf16* __restrict__ wo, float* __restrict__ bias) {
  int idx = blockIdx.x * 256 + threadIdx.x;
  if (idx < 256 * 256) wqkv[idx] = (__bf16)Wq[idx];              // q rows 0..255
  if (idx < 512 * 256) wqkv[256 * 256 + idx] = (__bf16)Wkv[idx]; // k 256..511, v 512..767
  if (idx < 256 * 256) wo[idx] = (__bf16)Wo[idx];
  if (idx < 49 * 49) bias[idx] = pos[rel[idx * 2] * 13 + rel[idx * 2 + 1]];
}

__global__ __launch_bounds__(256, 2) void attn_kernel(
    const float* __restrict__ x, const __bf16* __restrict__ wqkv,
    const __bf16* __restrict__ wo, const float* __restrict__ bias_g,
    const float* __restrict__ bo_g, float* __restrict__ outg,
    float* __restrict__ attng) {
  extern __shared__ char smem[];
  __bf16* xwT = (__bf16*)smem;
  __bf16* aoT = (__bf16*)smem;
  float* bias_s = (float*)(smem + BIAS_OFF);
  float* bo_s   = (float*)(smem + BO_OFF);

  const int tid = threadIdx.x;
  const int bid = blockIdx.x;
  // XCD-aware swizzle: 4096 blocks, 8 XCDs round-robin -> each XCD gets 512
  // consecutive works (same image / neighboring windows -> L2 line sharing).
  const int work = (bid & 7) * 512 + (bid >> 3);
  const int b  = work >> 8;
  const int i1 = (work >> 4) & 15;
  const int i2 = work & 15;
  const int r0 = i1 * 7, c0 = i2 * 7;
  const int wave = tid >> 6, lane = tid & 63;
  const int l31 = lane & 31, g2 = lane >> 5;
  const int c16 = lane & 15, g4 = lane >> 4;
  char* slice = smem + wave * SLICE_B;

  // ---------------- phase 0: stage x window (bf16, transposed), bias, bo ----------------
  {
    const int n = tid & 63, cb = tid >> 6;
    const int pr = n / 7, pc = n - pr * 7;
    const float* xg = x + (size_t)b * 256 * 12544 + (size_t)(r0 + pr) * 112 + (c0 + pc);
#pragma unroll 8
    for (int it = 0; it < 64; ++it) {
      const int c = it * 4 + cb;
      float v = 0.f;
      if (n < NPOS) v = xg[(size_t)c * 12544];
      xwT[n * XWT_PITCH + c] = (__bf16)v;
    }
    for (int i = tid; i < 2401; i += 256) bias_s[i] = bias_g[i];
    if (tid < 256) bo_s[tid] = bo_g[tid];
  }
  __syncthreads();

  // ---------------- GEMM1 B-fragments (xw) -> registers, then xwT is dead ----------------
  bf16x8 Bf0[16], Bf1[16];
  {
    const __bf16* Bp = xwT + l31 * XWT_PITCH + g2 * 8;
#pragma unroll
    for (int ks = 0; ks < 16; ++ks) {
      Bf0[ks] = *(const bf16x8*)(Bp + ks * 16);
      Bf1[ks] = *(const bf16x8*)(Bp + 32 * XWT_PITCH + ks * 16);
    }
  }
  __syncthreads();  // all waves hold B-frags; slices may now be written

  // ---------------- GEMM1-v: wave computes v rows of its own 2 heads ----------------
  char* vsb = slice + VS_OFF;
  {
    const __bf16* Ap0 = wqkv + (size_t)(512 + 64 * wave + l31) * 256 + g2 * 8;
    const __bf16* Ap1 = Ap0 + 32 * 256;
    f32x16 a00 = zero16(), a01 = zero16(), a10 = zero16(), a11 = zero16();
#pragma unroll
    for (int ks = 0; ks < 16; ++ks) {
      bf16x8 A0 = *(const bf16x8*)(Ap0 + ks * 16);
      bf16x8 A1 = *(const bf16x8*)(Ap1 + ks * 16);
      a00 = __builtin_amdgcn_mfma_f32_32x32x16_bf16(A0, Bf0[ks], a00, 0, 0, 0);
      a01 = __builtin_amdgcn_mfma_f32_32x32x16_bf16(A0, Bf1[ks], a01, 0, 0, 0);
      a10 = __builtin_amdgcn_mfma_f32_32x32x16_bf16(A1, Bf0[ks], a10, 0, 0, 0);
      a11 = __builtin_amdgcn_mfma_f32_32x32x16_bf16(A1, Bf1[ks], a11, 0, 0, 0);
    }
#pragma unroll
    for (int rg = 0; rg < 16; ++rg) {
      const int dd = (rg & 3) + 8 * (rg >> 2) + 4 * g2;
      *(__bf16*)(vsb + dd * VS_ROW_B + l31 * 2)              = (__bf16)a00[rg];
      *(__bf16*)(vsb + dd * VS_ROW_B + 64 + l31 * 2)         = (__bf16)a01[rg];
      *(__bf16*)(vsb + (32 + dd) * VS_ROW_B + l31 * 2)       = (__bf16)a10[rg];
      *(__bf16*)(vsb + (32 + dd) * VS_ROW_B + 64 + l31 * 2)  = (__bf16)a11[rg];
    }
  }
  // v B-fragments for PV -> registers (vs region is about to be clobbered by q/k)
  bf16x8 vf[2][2][2];
#pragma unroll
  for (int hh = 0; hh < 2; ++hh)
#pragma unroll
    for (int nt = 0; nt < 2; ++nt)
#pragma unroll
      for (int ks = 0; ks < 2; ++ks)
        vf[hh][nt][ks] = *(const bf16x8*)(vsb + (hh * 32 + nt * 16 + c16) * VS_ROW_B + ks * 64 + g4 * 16);
  asm volatile("s_waitcnt lgkmcnt(0)" ::: "memory");
  __builtin_amdgcn_sched_barrier(0);

  // ---------------- GEMM1-q and GEMM1-k into wave slice [pos][dd] ----------------
#pragma unroll 1
  for (int qk = 0; qk < 2; ++qk) {
    const int rowbase = qk * 256 + 64 * wave;
    const int koff = qk * 64;  // ELEMENT offset of the k region within a row
    const __bf16* Ap0 = wqkv + (size_t)(rowbase + l31) * 256 + g2 * 8;
    const __bf16* Ap1 = Ap0 + 32 * 256;
    f32x16 a00 = zero16(), a01 = zero16(), a10 = zero16(), a11 = zero16();
#pragma unroll
    for (int ks = 0; ks < 16; ++ks) {
      bf16x8 A0 = *(const bf16x8*)(Ap0 + ks * 16);
      bf16x8 A1 = *(const bf16x8*)(Ap1 + ks * 16);
      a00 = __builtin_amdgcn_mfma_f32_32x32x16_bf16(A0, Bf0[ks], a00, 0, 0, 0);
      a01 = __builtin_amdgcn_mfma_f32_32x32x16_bf16(A0, Bf1[ks], a01, 0, 0, 0);
      a10 = __builtin_amdgcn_mfma_f32_32x32x16_bf16(A1, Bf0[ks], a10, 0, 0, 0);
      a11 = __builtin_amdgcn_mfma_f32_32x32x16_bf16(A1, Bf1[ks], a11, 0, 0, 0);
    }
#define STORE_QK(ACC, P_, NT)                                                  \
    {                                                                          \
      const int n_ = (NT) * 32 + l31;                                          \
      _Pragma("unroll") for (int rb = 0; rb < 4; ++rb) {                       \
        const int ddb = koff + (P_) * 32 + rb * 8 + g2 * 4;                    \
        bf16x4 v4;                                                             \
        v4[0] = (__bf16)ACC[rb * 4 + 0]; v4[1] = (__bf16)ACC[rb * 4 + 1];      \
        v4[2] = (__bf16)ACC[rb * 4 + 2]; v4[3] = (__bf16)ACC[rb * 4 + 3];      \
        *(bf16x4*)(slice + n_ * QK_ROW_B + ddb * 2) = v4;                      \
      }                                                                        \
    }
    STORE_QK(a00, 0, 0)
    STORE_QK(a01, 0, 1)
    STORE_QK(a10, 1, 0)
    STORE_QK(a11, 1, 1)
  }
  // q/k A/B fragments for both heads -> registers (qk region reused for P next)
  bf16x8 qf[2][4], kf[2][4];
#pragma unroll
  for (int hh = 0; hh < 2; ++hh)
#pragma unroll
    for (int t = 0; t < 4; ++t) {
      qf[hh][t] = *(const bf16x8*)(slice + (t * 16 + c16) * QK_ROW_B + hh * 64 + g4 * 16);
      kf[hh][t] = *(const bf16x8*)(slice + (t * 16 + c16) * QK_ROW_B + 128 + hh * 64 + g4 * 16);
    }
  asm volatile("s_waitcnt lgkmcnt(0)" ::: "memory");
  __builtin_amdgcn_sched_barrier(0);

  // ---------------- attention: 2 heads per wave, barrier-free ----------------
  f32x4 pacc[2][4][2];
  char* Pbase = slice + P_OFF;
#pragma unroll
  for (int hh = 0; hh < 2; ++hh) {
    const int h = wave * 2 + hh;
    f32x4 dacc[4][4];
    const f32x4 z4 = {0.f, 0.f, 0.f, 0.f};
#pragma unroll
    for (int mt = 0; mt < 4; ++mt)
#pragma unroll
      for (int nt = 0; nt < 4; ++nt)
        dacc[mt][nt] = __builtin_amdgcn_mfma_f32_16x16x32_bf16(qf[hh][mt], kf[hh][nt], z4, 0, 0, 0);

    // softmax (fp32) + attn-output write + normalized P (bf16, XOR-swizzled LDS)
#pragma unroll
    for (int mt = 0; mt < 4; ++mt) {
#pragma unroll
      for (int r = 0; r < 4; ++r) {
        const int i = mt * 16 + g4 * 4 + r;
        float v[4];
#pragma unroll
        for (int nt = 0; nt < 4; ++nt) {
          const int j = nt * 16 + c16;
          float val = dacc[mt][nt][r] * SCALE_F;
          if (j < NPOS) {
            if (i < NPOS) val += bias_s[i * 49 + j];
          } else {
            val = -1e30f;
          }
          v[nt] = val;
        }
        float m = fmaxf(fmaxf(v[0], v[1]), fmaxf(v[2], v[3]));
        m = fmaxf(m, __shfl_xor(m, 1)); m = fmaxf(m, __shfl_xor(m, 2));
        m = fmaxf(m, __shfl_xor(m, 4)); m = fmaxf(m, __shfl_xor(m, 8));
        float p[4]; float s = 0.f;
#pragma unroll
        for (int nt = 0; nt < 4; ++nt) { p[nt] = __expf(v[nt] - m); s += p[nt]; }
        s += __shfl_xor(s, 1); s += __shfl_xor(s, 2);
        s += __shfl_xor(s, 4); s += __shfl_xor(s, 8);
        const float inv = 1.f / s;
        float* ap = attng + ((size_t)(work * NHEADS + h) * 49 + i) * 49;
#pragma unroll
        for (int nt = 0; nt < 4; ++nt) {
          const int j = nt * 16 + c16;
          const float pi = p[nt] * inv;
          if (i < NPOS && j < NPOS) ap[j] = pi;
          *(__bf16*)(Pbase + i * 128 + 16 * ((j >> 3) ^ (i & 7)) + 2 * (j & 7)) = (__bf16)pi;
        }
      }
    }

    // PV: out_h[i][d] = sum_j P[i][j] * v[j][d]
#pragma unroll
    for (int mt = 0; mt < 4; ++mt) {
      const int i = mt * 16 + c16;
      bf16x8 pa0 = *(const bf16x8*)(Pbase + i * 128 + 16 * ((0 + g4) ^ (i & 7)));
      bf16x8 pa1 = *(const bf16x8*)(Pbase + i * 128 + 16 * ((4 + g4) ^ (i & 7)));
#pragma unroll
      for (int nt = 0; nt < 2; ++nt) {
        f32x4 acc = {0.f, 0.f, 0.f, 0.f};
        acc = __builtin_amdgcn_mfma_f32_16x16x32_bf16(pa0, vf[hh][nt][0], acc, 0, 0, 0);
        acc = __builtin_amdgcn_mfma_f32_16x16x32_bf16(pa1, vf[hh][nt][1], acc, 0, 0, 0);
        pacc[hh][mt][nt] = acc;
      }
    }
  }
  __syncthreads();  // all waves done with slices; reuse smem[0..33792) as aoT

  // ---------------- write attn_out^T [n][256] ----------------
#pragma unroll
  for (int hh = 0; hh < 2; ++hh) {
    const int h = wave * 2 + hh;
#pragma unroll
    for (int mt = 0; mt < 4; ++mt)
#pragma unroll
      for (int nt = 0; nt < 2; ++nt)
#pragma unroll
        for (int e = 0; e < 4; ++e) {
          const int i = mt * 16 + g4 * 4 + e;
          const int cc = h * 32 + nt * 16 + c16;
          aoT[i * AOT_PITCH + cc] = (__bf16)pacc[hh][mt][nt][e];
        }
  }
  __syncthreads();

  // ---------------- GEMM4: out[256][64] = Wo[256][256] @ aoT^T + bo ----------------
  {
    bf16x8 Cf0[16], Cf1[16];
    const __bf16* Bp = aoT + l31 * AOT_PITCH + g2 * 8;
#pragma unroll
    for (int ks = 0; ks < 16; ++ks) {
      Cf0[ks] = *(const bf16x8*)(Bp + ks * 16);
      Cf1[ks] = *(const bf16x8*)(Bp + 32 * AOT_PITCH + ks * 16);
    }
    const __bf16* Ap0 = wo + (size_t)(wave * 64 + l31) * 256 + g2 * 8;
    const __bf16* Ap1 = Ap0 + 32 * 256;
    f32x16 a00 = zero16(), a01 = zero16(), a10 = zero16(), a11 = zero16();
#pragma unroll
    for (int ks = 0; ks < 16; ++ks) {
      bf16x8 A0 = *(const bf16x8*)(Ap0 + ks * 16);
      bf16x8 A1 = *(const bf16x8*)(Ap1 + ks * 16);
      a00 = __builtin_amdgcn_mfma_f32_32x32x16_bf16(A0, Cf0[ks], a00, 0, 0, 0);
      a01 = __builtin_amdgcn_mfma_f32_32x32x16_bf16(A0, Cf1[ks], a01, 0, 0, 0);
      a10 = __builtin_amdgcn_mfma_f32_32x32x16_bf16(A1, Cf0[ks], a10, 0, 0, 0);
      a11 = __builtin_amdgcn_mfma_f32_32x32x16_bf16(A1, Cf1[ks], a11, 0, 0, 0);
    }
    float* og = outg + (size_t)b * 256 * 12544;
#define STORE_OUT(ACC, MT, NT)                                                    \
    {                                                                             \
      const int n_ = (NT) * 32 + l31;                                             \
      if (n_ < NPOS) {                                                            \
        const int pr_ = n_ / 7, pc_ = n_ - pr_ * 7;                               \
        float* orow = og + (size_t)(r0 + pr_) * 112 + (c0 + pc_);                 \
        _Pragma("unroll") for (int rg = 0; rg < 16; ++rg) {                       \
          const int o2 = wave * 64 + (MT) * 32 + (rg & 3) + 8 * (rg >> 2) + 4 * g2; \
          orow[(size_t)o2 * 12544] = ACC[rg] + bo_s[o2];                          \
        }                                                                         \
      }                                                                           \
    }
    STORE_OUT(a00, 0, 0)
    STORE_OUT(a01, 0, 1)
    STORE_OUT(a10, 1, 0)
    STORE_OUT(a11, 1, 1)
  }
}

extern "C" void kernel_launch(void* const* d_in, const int* in_sizes, int n_in,
                              void* d_out, int out_size, void* d_ws, size_t ws_size,
                              hipStream_t stream) {
  const float* x   = (const float*)d_in[0];
  const float* Wq  = (const float*)d_in[1];
  const float* Wkv = (const float*)d_in[2];
  const float* Wo  = (const float*)d_in[3];
  const float* bo  = (const float*)d_in[4];
  const float* pos = (const float*)d_in[5];
  const int*   rel = (const int*)d_in[6];

  float* outg  = (float*)d_out;
  float* attng = outg + (size_t)16 * 256 * 112 * 112;

  __bf16* wqkv = (__bf16*)d_ws;
  __bf16* wo   = wqkv + 768 * 256;
  float*  bias = (float*)(wo + 256 * 256);

  hipFuncSetAttribute((const void*)attn_kernel,
                      hipFuncAttributeMaxDynamicSharedMemorySize, LDS_BYTES);

  prep_kernel<<<dim3(512), dim3(256), 0, stream>>>(Wq, Wkv, Wo, pos, rel, wqkv, wo, bias);
  attn_kernel<<<dim3(4096), dim3(256), LDS_BYTES, stream>>>(x, wqkv, wo, bias, bo, outg, attng);
}

// Round 4
// 541.255 us; speedup vs baseline: 2.2630x; 1.3558x over previous
//
#include <hip/hip_runtime.h>
#include <hip/hip_bf16.h>

typedef __bf16 bf16x8 __attribute__((ext_vector_type(8)));
typedef __bf16 bf16x4 __attribute__((ext_vector_type(4)));
typedef float  f32x4  __attribute__((ext_vector_type(4)));
typedef float  f32x16 __attribute__((ext_vector_type(16)));

#define NPOS 49
#define NHEADS 8
#define SCALE_F 0.17677669529663687f

// ---- LDS layout ----
// 4 per-wave slices of SLICE_B bytes at smem[0..67584):
//   phase0/GEMM1-prologue: smem[0..33792) also holds xwT [64][264] bf16 (waves 0,1 slices)
//   per-wave slice: qk [64 pos][132 dd] bf16 (pitch 264 B; dd ELEMENTS: q=0..63, k=64..127)
//                   vs (transient) at slice+8192: [64 dd][68 pos] bf16 (pitch 136 B)
//                   P0 at slice+0, P1 at slice+8192: [64 i][128 B] swizzled bf16
//   epilogue: smem[0..33792) holds aoT [64][264] bf16
#define SLICE_B   16896
#define QK_ROW_B  264
#define VS_OFF    8192
#define VS_ROW_B  136
#define XWT_PITCH 264
#define AOT_PITCH 264
#define BIAS_OFF  67584
#define BO_OFF    77188
#define LDS_BYTES 78212

static __device__ __forceinline__ f32x16 zero16() {
  f32x16 z;
#pragma unroll
  for (int i = 0; i < 16; ++i) z[i] = 0.f;
  return z;
}

__global__ void prep_kernel(const float* __restrict__ Wq, const float* __restrict__ Wkv,
                            const float* __restrict__ Wo, const float* __restrict__ pos,
                            const int* __restrict__ rel, __bf16* __restrict__ wqkv,
                            __bf16* __restrict__ wo, float* __restrict__ bias) {
  int idx = blockIdx.x * 256 + threadIdx.x;
  if (idx < 256 * 256) wqkv[idx] = (__bf16)Wq[idx];              // q rows 0..255
  if (idx < 512 * 256) wqkv[256 * 256 + idx] = (__bf16)Wkv[idx]; // k 256..511, v 512..767
  if (idx < 256 * 256) wo[idx] = (__bf16)Wo[idx];
  if (idx < 49 * 49) bias[idx] = pos[rel[idx * 2] * 13 + rel[idx * 2 + 1]];
}

__global__ __launch_bounds__(256, 2) void attn_kernel(
    const float* __restrict__ x, const __bf16* __restrict__ wqkv,
    const __bf16* __restrict__ wo, const float* __restrict__ bias_g,
    const float* __restrict__ bo_g, float* __restrict__ outg,
    float* __restrict__ attng) {
  extern __shared__ char smem[];
  __bf16* xwT = (__bf16*)smem;
  __bf16* aoT = (__bf16*)smem;
  float* bias_s = (float*)(smem + BIAS_OFF);
  float* bo_s   = (float*)(smem + BO_OFF);

  const int tid = threadIdx.x;
  const int bid = blockIdx.x;
  // XCD-aware swizzle: 4096 blocks, 8 XCDs round-robin -> each XCD gets 512
  // consecutive works (neighboring windows -> L2 line sharing).
  const int work = (bid & 7) * 512 + (bid >> 3);
  const int b  = work >> 8;
  const int i1 = (work >> 4) & 15;
  const int i2 = work & 15;
  const int r0 = i1 * 7, c0 = i2 * 7;
  const int wave = tid >> 6, lane = tid & 63;
  const int l31 = lane & 31, g2 = lane >> 5;
  const int c16 = lane & 15, g4 = lane >> 4;
  char* slice = smem + wave * SLICE_B;

  // ---------------- phase 0: stage x window (bf16, transposed), bias, bo ----------------
  {
    const int n = tid & 63, cb = tid >> 6;
    const int np = (n < NPOS) ? n : 0;           // clamp inactive lanes to pos 0 (no OOB)
    const float zf = (n < NPOS) ? 1.f : 0.f;
    const int pr = np / 7, pc = np - pr * 7;
    const float* xg = x + (size_t)b * 256 * 12544 + (size_t)(r0 + pr) * 112 + (c0 + pc);
    float tmp[32];
#pragma unroll
    for (int half = 0; half < 2; ++half) {
#pragma unroll
      for (int it = 0; it < 32; ++it)
        tmp[it] = xg[(size_t)((half * 32 + it) * 4 + cb) * 12544];
#pragma unroll
      for (int it = 0; it < 32; ++it)
        xwT[n * XWT_PITCH + (half * 32 + it) * 4 + cb] = (__bf16)(tmp[it] * zf);
    }
    const float4* bg4 = (const float4*)bias_g;
    for (int i = tid; i < 600; i += 256) ((float4*)bias_s)[i] = bg4[i];
    if (tid == 0) bias_s[2400] = bias_g[2400];
    bo_s[tid] = bo_g[tid];
  }
  __syncthreads();

  // ---------------- GEMM1 B-fragments (xw) -> registers, then xwT is dead ----------------
  bf16x8 Bf0[16], Bf1[16];
  {
    const __bf16* Bp = xwT + l31 * XWT_PITCH + g2 * 8;
#pragma unroll
    for (int ks = 0; ks < 16; ++ks) {
      Bf0[ks] = *(const bf16x8*)(Bp + ks * 16);
      Bf1[ks] = *(const bf16x8*)(Bp + 32 * XWT_PITCH + ks * 16);
    }
  }
  __syncthreads();  // all waves hold B-frags; slices may now be written

  // ---------------- GEMM1-v: wave computes v rows of its own 2 heads ----------------
  char* vsb = slice + VS_OFF;
  {
    const __bf16* Ap0 = wqkv + (size_t)(512 + 64 * wave + l31) * 256 + g2 * 8;
    const __bf16* Ap1 = Ap0 + 32 * 256;
    f32x16 a00 = zero16(), a01 = zero16(), a10 = zero16(), a11 = zero16();
    __builtin_amdgcn_s_setprio(1);
#pragma unroll
    for (int ks = 0; ks < 16; ++ks) {
      bf16x8 A0 = *(const bf16x8*)(Ap0 + ks * 16);
      bf16x8 A1 = *(const bf16x8*)(Ap1 + ks * 16);
      a00 = __builtin_amdgcn_mfma_f32_32x32x16_bf16(A0, Bf0[ks], a00, 0, 0, 0);
      a01 = __builtin_amdgcn_mfma_f32_32x32x16_bf16(A0, Bf1[ks], a01, 0, 0, 0);
      a10 = __builtin_amdgcn_mfma_f32_32x32x16_bf16(A1, Bf0[ks], a10, 0, 0, 0);
      a11 = __builtin_amdgcn_mfma_f32_32x32x16_bf16(A1, Bf1[ks], a11, 0, 0, 0);
    }
    __builtin_amdgcn_s_setprio(0);
#pragma unroll
    for (int rg = 0; rg < 16; ++rg) {
      const int dd = (rg & 3) + 8 * (rg >> 2) + 4 * g2;
      *(__bf16*)(vsb + dd * VS_ROW_B + l31 * 2)              = (__bf16)a00[rg];
      *(__bf16*)(vsb + dd * VS_ROW_B + 64 + l31 * 2)         = (__bf16)a01[rg];
      *(__bf16*)(vsb + (32 + dd) * VS_ROW_B + l31 * 2)       = (__bf16)a10[rg];
      *(__bf16*)(vsb + (32 + dd) * VS_ROW_B + 64 + l31 * 2)  = (__bf16)a11[rg];
    }
  }
  // v B-fragments for PV -> registers (vs region is about to be clobbered by q/k)
  bf16x8 vf[2][2][2];
#pragma unroll
  for (int hh = 0; hh < 2; ++hh)
#pragma unroll
    for (int nt = 0; nt < 2; ++nt)
#pragma unroll
      for (int ks = 0; ks < 2; ++ks)
        vf[hh][nt][ks] = *(const bf16x8*)(vsb + (hh * 32 + nt * 16 + c16) * VS_ROW_B + ks * 64 + g4 * 16);
  asm volatile("s_waitcnt lgkmcnt(0)" ::: "memory");
  __builtin_amdgcn_sched_barrier(0x20);  // only VMEM_READ (weight loads) may cross

  // ---------------- GEMM1-q and GEMM1-k into wave slice [pos][dd] (unrolled) ----------------
#pragma unroll
  for (int qk = 0; qk < 2; ++qk) {
    const int rowbase = qk * 256 + 64 * wave;
    const int koff = qk * 64;  // ELEMENT offset of the k region within a row
    const __bf16* Ap0 = wqkv + (size_t)(rowbase + l31) * 256 + g2 * 8;
    const __bf16* Ap1 = Ap0 + 32 * 256;
    f32x16 a00 = zero16(), a01 = zero16(), a10 = zero16(), a11 = zero16();
    __builtin_amdgcn_s_setprio(1);
#pragma unroll
    for (int ks = 0; ks < 16; ++ks) {
      bf16x8 A0 = *(const bf16x8*)(Ap0 + ks * 16);
      bf16x8 A1 = *(const bf16x8*)(Ap1 + ks * 16);
      a00 = __builtin_amdgcn_mfma_f32_32x32x16_bf16(A0, Bf0[ks], a00, 0, 0, 0);
      a01 = __builtin_amdgcn_mfma_f32_32x32x16_bf16(A0, Bf1[ks], a01, 0, 0, 0);
      a10 = __builtin_amdgcn_mfma_f32_32x32x16_bf16(A1, Bf0[ks], a10, 0, 0, 0);
      a11 = __builtin_amdgcn_mfma_f32_32x32x16_bf16(A1, Bf1[ks], a11, 0, 0, 0);
    }
    __builtin_amdgcn_s_setprio(0);
#define STORE_QK(ACC, P_, NT)                                                  \
    {                                                                          \
      const int n_ = (NT) * 32 + l31;                                          \
      _Pragma("unroll") for (int rb = 0; rb < 4; ++rb) {                       \
        const int ddb = koff + (P_) * 32 + rb * 8 + g2 * 4;                    \
        bf16x4 v4;                                                             \
        v4[0] = (__bf16)ACC[rb * 4 + 0]; v4[1] = (__bf16)ACC[rb * 4 + 1];      \
        v4[2] = (__bf16)ACC[rb * 4 + 2]; v4[3] = (__bf16)ACC[rb * 4 + 3];      \
        *(bf16x4*)(slice + n_ * QK_ROW_B + ddb * 2) = v4;                      \
      }                                                                        \
    }
    STORE_QK(a00, 0, 0)
    STORE_QK(a01, 0, 1)
    STORE_QK(a10, 1, 0)
    STORE_QK(a11, 1, 1)
  }
  // q/k A/B fragments for both heads -> registers (qk region reused for P next)
  bf16x8 qf[2][4], kf[2][4];
#pragma unroll
  for (int hh = 0; hh < 2; ++hh)
#pragma unroll
    for (int t = 0; t < 4; ++t) {
      qf[hh][t] = *(const bf16x8*)(slice + (t * 16 + c16) * QK_ROW_B + hh * 64 + g4 * 16);
      kf[hh][t] = *(const bf16x8*)(slice + (t * 16 + c16) * QK_ROW_B + 128 + hh * 64 + g4 * 16);
    }
  asm volatile("s_waitcnt lgkmcnt(0)" ::: "memory");
  __builtin_amdgcn_sched_barrier(0x20);

  // ---------------- attention: both heads interleaved, barrier-free ----------------
  f32x4 pacc[2][4][2];
  char* Pb0 = slice;           // qk rows 0..31 region (fragments already in regs)
  char* Pb1 = slice + 8192;    // qk rows 32..63 / vs region
  {
    const f32x4 z4 = {0.f, 0.f, 0.f, 0.f};
    f32x4 dacc[2][4][4];
    __builtin_amdgcn_s_setprio(1);
#pragma unroll
    for (int hh = 0; hh < 2; ++hh)
#pragma unroll
      for (int mt = 0; mt < 4; ++mt)
#pragma unroll
        for (int nt = 0; nt < 4; ++nt)
          dacc[hh][mt][nt] = __builtin_amdgcn_mfma_f32_16x16x32_bf16(qf[hh][mt], kf[hh][nt], z4, 0, 0, 0);
    __builtin_amdgcn_s_setprio(0);

    const int h0 = wave * 2;
    // softmax (fp32): both heads' reduce chains interleaved for ILP
#pragma unroll
    for (int mt = 0; mt < 4; ++mt) {
#pragma unroll
      for (int r = 0; r < 4; ++r) {
        const int i = mt * 16 + g4 * 4 + r;
        float vv[2][4];
#pragma unroll
        for (int hh = 0; hh < 2; ++hh)
#pragma unroll
          for (int nt = 0; nt < 4; ++nt) {
            const int j = nt * 16 + c16;
            float val = dacc[hh][mt][nt][r] * SCALE_F;
            if (j < NPOS) {
              if (i < NPOS) val += bias_s[i * 49 + j];
            } else {
              val = -1e30f;
            }
            vv[hh][nt] = val;
          }
        float m0 = fmaxf(fmaxf(vv[0][0], vv[0][1]), fmaxf(vv[0][2], vv[0][3]));
        float m1 = fmaxf(fmaxf(vv[1][0], vv[1][1]), fmaxf(vv[1][2], vv[1][3]));
        m0 = fmaxf(m0, __shfl_xor(m0, 1)); m1 = fmaxf(m1, __shfl_xor(m1, 1));
        m0 = fmaxf(m0, __shfl_xor(m0, 2)); m1 = fmaxf(m1, __shfl_xor(m1, 2));
        m0 = fmaxf(m0, __shfl_xor(m0, 4)); m1 = fmaxf(m1, __shfl_xor(m1, 4));
        m0 = fmaxf(m0, __shfl_xor(m0, 8)); m1 = fmaxf(m1, __shfl_xor(m1, 8));
        float p0[4], p1[4], s0 = 0.f, s1 = 0.f;
#pragma unroll
        for (int nt = 0; nt < 4; ++nt) {
          p0[nt] = __expf(vv[0][nt] - m0); s0 += p0[nt];
          p1[nt] = __expf(vv[1][nt] - m1); s1 += p1[nt];
        }
        s0 += __shfl_xor(s0, 1); s1 += __shfl_xor(s1, 1);
        s0 += __shfl_xor(s0, 2); s1 += __shfl_xor(s1, 2);
        s0 += __shfl_xor(s0, 4); s1 += __shfl_xor(s1, 4);
        s0 += __shfl_xor(s0, 8); s1 += __shfl_xor(s1, 8);
        const float inv0 = 1.f / s0, inv1 = 1.f / s1;
        if (i < NPOS) {
          float* ap0 = attng + ((size_t)(work * NHEADS + h0) * 49 + i) * 49;
          float* ap1 = ap0 + 49 * 49;
#pragma unroll
          for (int nt = 0; nt < 4; ++nt) {
            const int j = nt * 16 + c16;
            if (j < NPOS) { ap0[j] = p0[nt] * inv0; ap1[j] = p1[nt] * inv1; }
          }
        }
#pragma unroll
        for (int nt = 0; nt < 4; ++nt) {
          const int j = nt * 16 + c16;
          *(__bf16*)(Pb0 + i * 128 + 16 * ((j >> 3) ^ (i & 7)) + 2 * (j & 7)) = (__bf16)(p0[nt] * inv0);
          *(__bf16*)(Pb1 + i * 128 + 16 * ((j >> 3) ^ (i & 7)) + 2 * (j & 7)) = (__bf16)(p1[nt] * inv1);
        }
      }
    }

    // PV: out_h[i][d] = sum_j P[i][j] * v[j][d]
    __builtin_amdgcn_s_setprio(1);
#pragma unroll
    for (int hh = 0; hh < 2; ++hh) {
      char* Pb = hh ? Pb1 : Pb0;
#pragma unroll
      for (int mt = 0; mt < 4; ++mt) {
        const int i = mt * 16 + c16;
        bf16x8 pa0 = *(const bf16x8*)(Pb + i * 128 + 16 * ((0 + g4) ^ (i & 7)));
        bf16x8 pa1 = *(const bf16x8*)(Pb + i * 128 + 16 * ((4 + g4) ^ (i & 7)));
#pragma unroll
        for (int nt = 0; nt < 2; ++nt) {
          f32x4 acc = {0.f, 0.f, 0.f, 0.f};
          acc = __builtin_amdgcn_mfma_f32_16x16x32_bf16(pa0, vf[hh][nt][0], acc, 0, 0, 0);
          acc = __builtin_amdgcn_mfma_f32_16x16x32_bf16(pa1, vf[hh][nt][1], acc, 0, 0, 0);
          pacc[hh][mt][nt] = acc;
        }
      }
    }
    __builtin_amdgcn_s_setprio(0);
  }
  __syncthreads();  // all waves done with slices; reuse smem[0..33792) as aoT

  // ---------------- write attn_out^T [n][256] ----------------
#pragma unroll
  for (int hh = 0; hh < 2; ++hh) {
    const int h = wave * 2 + hh;
#pragma unroll
    for (int mt = 0; mt < 4; ++mt)
#pragma unroll
      for (int nt = 0; nt < 2; ++nt)
#pragma unroll
        for (int e = 0; e < 4; ++e) {
          const int i = mt * 16 + g4 * 4 + e;
          const int cc = h * 32 + nt * 16 + c16;
          aoT[i * AOT_PITCH + cc] = (__bf16)pacc[hh][mt][nt][e];
        }
  }
  __syncthreads();

  // ---------------- GEMM4: out[256][64] = Wo[256][256] @ aoT^T + bo ----------------
  {
    bf16x8 Cf0[16], Cf1[16];
    const __bf16* Bp = aoT + l31 * AOT_PITCH + g2 * 8;
#pragma unroll
    for (int ks = 0; ks < 16; ++ks) {
      Cf0[ks] = *(const bf16x8*)(Bp + ks * 16);
      Cf1[ks] = *(const bf16x8*)(Bp + 32 * AOT_PITCH + ks * 16);
    }
    const __bf16* Ap0 = wo + (size_t)(wave * 64 + l31) * 256 + g2 * 8;
    const __bf16* Ap1 = Ap0 + 32 * 256;
    f32x16 a00 = zero16(), a01 = zero16(), a10 = zero16(), a11 = zero16();
    __builtin_amdgcn_s_setprio(1);
#pragma unroll
    for (int ks = 0; ks < 16; ++ks) {
      bf16x8 A0 = *(const bf16x8*)(Ap0 + ks * 16);
      bf16x8 A1 = *(const bf16x8*)(Ap1 + ks * 16);
      a00 = __builtin_amdgcn_mfma_f32_32x32x16_bf16(A0, Cf0[ks], a00, 0, 0, 0);
      a01 = __builtin_amdgcn_mfma_f32_32x32x16_bf16(A0, Cf1[ks], a01, 0, 0, 0);
      a10 = __builtin_amdgcn_mfma_f32_32x32x16_bf16(A1, Cf0[ks], a10, 0, 0, 0);
      a11 = __builtin_amdgcn_mfma_f32_32x32x16_bf16(A1, Cf1[ks], a11, 0, 0, 0);
    }
    __builtin_amdgcn_s_setprio(0);
    float* og = outg + (size_t)b * 256 * 12544;
#define STORE_OUT(ACC, MT, NT)                                                    \
    {                                                                             \
      const int n_ = (NT) * 32 + l31;                                             \
      if (n_ < NPOS) {                                                            \
        const int pr_ = n_ / 7, pc_ = n_ - pr_ * 7;                               \
        float* orow = og + (size_t)(r0 + pr_) * 112 + (c0 + pc_);                 \
        _Pragma("unroll") for (int rg = 0; rg < 16; ++rg) {                       \
          const int o2 = wave * 64 + (MT) * 32 + (rg & 3) + 8 * (rg >> 2) + 4 * g2; \
          orow[(size_t)o2 * 12544] = ACC[rg] + bo_s[o2];                          \
        }                                                                         \
      }                                                                           \
    }
    STORE_OUT(a00, 0, 0)
    STORE_OUT(a01, 0, 1)
    STORE_OUT(a10, 1, 0)
    STORE_OUT(a11, 1, 1)
  }
}

extern "C" void kernel_launch(void* const* d_in, const int* in_sizes, int n_in,
                              void* d_out, int out_size, void* d_ws, size_t ws_size,
                              hipStream_t stream) {
  const float* x   = (const float*)d_in[0];
  const float* Wq  = (const float*)d_in[1];
  const float* Wkv = (const float*)d_in[2];
  const float* Wo  = (const float*)d_in[3];
  const float* bo  = (const float*)d_in[4];
  const float* pos = (const float*)d_in[5];
  const int*   rel = (const int*)d_in[6];

  float* outg  = (float*)d_out;
  float* attng = outg + (size_t)16 * 256 * 112 * 112;

  __bf16* wqkv = (__bf16*)d_ws;
  __bf16* wo   = wqkv + 768 * 256;
  float*  bias = (float*)(wo + 256 * 256);

  hipFuncSetAttribute((const void*)attn_kernel,
                      hipFuncAttributeMaxDynamicSharedMemorySize, LDS_BYTES);

  prep_kernel<<<dim3(512), dim3(256), 0, stream>>>(Wq, Wkv, Wo, pos, rel, wqkv, wo, bias);
  attn_kernel<<<dim3(4096), dim3(256), LDS_BYTES, stream>>>(x, wqkv, wo, bias, bo, outg, attng);
}

// Round 5
// 487.181 us; speedup vs baseline: 2.5141x; 1.1110x over previous
//
#include <hip/hip_runtime.h>
#include <hip/hip_bf16.h>

typedef __bf16 bf16x8 __attribute__((ext_vector_type(8)));
typedef __bf16 bf16x4 __attribute__((ext_vector_type(4)));
typedef float  f32x4  __attribute__((ext_vector_type(4)));
typedef float  f32x16 __attribute__((ext_vector_type(16)));

#define NPOS 49
#define NHEADS 8
#define SCALE_F 0.17677669529663687f

// ---- kernel A LDS layout ----
#define SLICE_B   16896
#define QK_ROW_B  264
#define VS_OFF    8192
#define VS_ROW_B  136
#define XWT_PITCH 264
#define AOT_PITCH 264
#define BIAS_OFF  67584
#define BO_OFF    77188
#define LDS_BYTES 78212

static __device__ __forceinline__ f32x16 zero16() {
  f32x16 z;
#pragma unroll
  for (int i = 0; i < 16; ++i) z[i] = 0.f;
  return z;
}

__global__ void prep_kernel(const float* __restrict__ Wq, const float* __restrict__ Wkv,
                            const float* __restrict__ Wo, const float* __restrict__ pos,
                            const int* __restrict__ rel, __bf16* __restrict__ wqkv,
                            __bf16* __restrict__ wo, float* __restrict__ bias) {
  int idx = blockIdx.x * 256 + threadIdx.x;
  if (idx < 256 * 256) wqkv[idx] = (__bf16)Wq[idx];              // q rows 0..255
  if (idx < 512 * 256) wqkv[256 * 256 + idx] = (__bf16)Wkv[idx]; // k 256..511, v 512..767
  if (idx < 256 * 256) wo[idx] = (__bf16)Wo[idx];
  if (idx < 49 * 49) bias[idx] = pos[rel[idx * 2] * 13 + rel[idx * 2 + 1]];
}

// MODE 0: monolithic (in-kernel Wo GEMM + scattered out writes)  [fallback]
// MODE 1: ends at PV; writes attn_out (pre-Wo) to aoT_g[win][49][256] bf16
template <int MODE>
__global__ __launch_bounds__(256, 2) void attn_kernel(
    const float* __restrict__ x, const __bf16* __restrict__ wqkv,
    const __bf16* __restrict__ wo, const float* __restrict__ bias_g,
    const float* __restrict__ bo_g, float* __restrict__ outg,
    float* __restrict__ attng, __bf16* __restrict__ aoT_g) {
  extern __shared__ char smem[];
  __bf16* xwT = (__bf16*)smem;
  __bf16* aoT = (__bf16*)smem;
  float* bias_s = (float*)(smem + BIAS_OFF);
  float* bo_s   = (float*)(smem + BO_OFF);

  const int tid = threadIdx.x;
  const int bid = blockIdx.x;
  // XCD-aware swizzle: consecutive works land on the same XCD.
  const int work = (bid & 7) * 512 + (bid >> 3);
  const int b  = work >> 8;
  const int i1 = (work >> 4) & 15;
  const int i2 = work & 15;
  const int r0 = i1 * 7, c0 = i2 * 7;
  const int wave = tid >> 6, lane = tid & 63;
  const int l31 = lane & 31, g2 = lane >> 5;
  const int c16 = lane & 15, g4 = lane >> 4;
  char* slice = smem + wave * SLICE_B;

  // ---------------- phase 0: stage x window (bf16, transposed), bias ----------------
  {
    const int n = tid & 63, cb = tid >> 6;
    const int np = (n < NPOS) ? n : 0;           // clamp inactive lanes (no OOB)
    const float zf = (n < NPOS) ? 1.f : 0.f;
    const int pr = np / 7, pc = np - pr * 7;
    const float* xg = x + (size_t)b * 256 * 12544 + (size_t)(r0 + pr) * 112 + (c0 + pc);
    float tmp[64];
#pragma unroll
    for (int it = 0; it < 64; ++it)
      tmp[it] = xg[(size_t)(it * 4 + cb) * 12544];
#pragma unroll
    for (int it = 0; it < 64; ++it)
      xwT[n * XWT_PITCH + it * 4 + cb] = (__bf16)(tmp[it] * zf);
    const float4* bg4 = (const float4*)bias_g;
    for (int i = tid; i < 600; i += 256) ((float4*)bias_s)[i] = bg4[i];
    if (tid == 0) bias_s[2400] = bias_g[2400];
    if constexpr (MODE == 0) bo_s[tid] = bo_g[tid];
  }
  __syncthreads();

  // ---------------- GEMM1 B-fragments (xw) -> registers ----------------
  bf16x8 Bf0[16], Bf1[16];
  {
    const __bf16* Bp = xwT + l31 * XWT_PITCH + g2 * 8;
#pragma unroll
    for (int ks = 0; ks < 16; ++ks) {
      Bf0[ks] = *(const bf16x8*)(Bp + ks * 16);
      Bf1[ks] = *(const bf16x8*)(Bp + 32 * XWT_PITCH + ks * 16);
    }
  }
  __syncthreads();  // all waves hold B-frags; slices may now be written

  // ---------------- GEMM1-v: wave computes v rows of its own 2 heads ----------------
  char* vsb = slice + VS_OFF;
  {
    const __bf16* Ap0 = wqkv + (size_t)(512 + 64 * wave + l31) * 256 + g2 * 8;
    const __bf16* Ap1 = Ap0 + 32 * 256;
    f32x16 a00 = zero16(), a01 = zero16(), a10 = zero16(), a11 = zero16();
    __builtin_amdgcn_s_setprio(1);
#pragma unroll
    for (int ks = 0; ks < 16; ++ks) {
      bf16x8 A0 = *(const bf16x8*)(Ap0 + ks * 16);
      bf16x8 A1 = *(const bf16x8*)(Ap1 + ks * 16);
      a00 = __builtin_amdgcn_mfma_f32_32x32x16_bf16(A0, Bf0[ks], a00, 0, 0, 0);
      a01 = __builtin_amdgcn_mfma_f32_32x32x16_bf16(A0, Bf1[ks], a01, 0, 0, 0);
      a10 = __builtin_amdgcn_mfma_f32_32x32x16_bf16(A1, Bf0[ks], a10, 0, 0, 0);
      a11 = __builtin_amdgcn_mfma_f32_32x32x16_bf16(A1, Bf1[ks], a11, 0, 0, 0);
    }
    __builtin_amdgcn_s_setprio(0);
#pragma unroll
    for (int rg = 0; rg < 16; ++rg) {
      const int dd = (rg & 3) + 8 * (rg >> 2) + 4 * g2;
      *(__bf16*)(vsb + dd * VS_ROW_B + l31 * 2)              = (__bf16)a00[rg];
      *(__bf16*)(vsb + dd * VS_ROW_B + 64 + l31 * 2)         = (__bf16)a01[rg];
      *(__bf16*)(vsb + (32 + dd) * VS_ROW_B + l31 * 2)       = (__bf16)a10[rg];
      *(__bf16*)(vsb + (32 + dd) * VS_ROW_B + 64 + l31 * 2)  = (__bf16)a11[rg];
    }
  }
  bf16x8 vf[2][2][2];
#pragma unroll
  for (int hh = 0; hh < 2; ++hh)
#pragma unroll
    for (int nt = 0; nt < 2; ++nt)
#pragma unroll
      for (int ks = 0; ks < 2; ++ks)
        vf[hh][nt][ks] = *(const bf16x8*)(vsb + (hh * 32 + nt * 16 + c16) * VS_ROW_B + ks * 64 + g4 * 16);
  asm volatile("s_waitcnt lgkmcnt(0)" ::: "memory");
  __builtin_amdgcn_sched_barrier(0x20);  // only VMEM_READ (weight loads) may cross

  // ---------------- GEMM1-q and GEMM1-k into wave slice [pos][dd] ----------------
#pragma unroll
  for (int qk = 0; qk < 2; ++qk) {
    const int rowbase = qk * 256 + 64 * wave;
    const int koff = qk * 64;  // ELEMENT offset of the k region within a row
    const __bf16* Ap0 = wqkv + (size_t)(rowbase + l31) * 256 + g2 * 8;
    const __bf16* Ap1 = Ap0 + 32 * 256;
    f32x16 a00 = zero16(), a01 = zero16(), a10 = zero16(), a11 = zero16();
    __builtin_amdgcn_s_setprio(1);
#pragma unroll
    for (int ks = 0; ks < 16; ++ks) {
      bf16x8 A0 = *(const bf16x8*)(Ap0 + ks * 16);
      bf16x8 A1 = *(const bf16x8*)(Ap1 + ks * 16);
      a00 = __builtin_amdgcn_mfma_f32_32x32x16_bf16(A0, Bf0[ks], a00, 0, 0, 0);
      a01 = __builtin_amdgcn_mfma_f32_32x32x16_bf16(A0, Bf1[ks], a01, 0, 0, 0);
      a10 = __builtin_amdgcn_mfma_f32_32x32x16_bf16(A1, Bf0[ks], a10, 0, 0, 0);
      a11 = __builtin_amdgcn_mfma_f32_32x32x16_bf16(A1, Bf1[ks], a11, 0, 0, 0);
    }
    __builtin_amdgcn_s_setprio(0);
#define STORE_QK(ACC, P_, NT)                                                  \
    {                                                                          \
      const int n_ = (NT) * 32 + l31;                                          \
      _Pragma("unroll") for (int rb = 0; rb < 4; ++rb) {                       \
        const int ddb = koff + (P_) * 32 + rb * 8 + g2 * 4;                    \
        bf16x4 v4;                                                             \
        v4[0] = (__bf16)ACC[rb * 4 + 0]; v4[1] = (__bf16)ACC[rb * 4 + 1];      \
        v4[2] = (__bf16)ACC[rb * 4 + 2]; v4[3] = (__bf16)ACC[rb * 4 + 3];      \
        *(bf16x4*)(slice + n_ * QK_ROW_B + ddb * 2) = v4;                      \
      }                                                                        \
    }
    STORE_QK(a00, 0, 0)
    STORE_QK(a01, 0, 1)
    STORE_QK(a10, 1, 0)
    STORE_QK(a11, 1, 1)
  }
  bf16x8 qf[2][4], kf[2][4];
#pragma unroll
  for (int hh = 0; hh < 2; ++hh)
#pragma unroll
    for (int t = 0; t < 4; ++t) {
      qf[hh][t] = *(const bf16x8*)(slice + (t * 16 + c16) * QK_ROW_B + hh * 64 + g4 * 16);
      kf[hh][t] = *(const bf16x8*)(slice + (t * 16 + c16) * QK_ROW_B + 128 + hh * 64 + g4 * 16);
    }
  asm volatile("s_waitcnt lgkmcnt(0)" ::: "memory");
  __builtin_amdgcn_sched_barrier(0x20);

  // ---------------- attention: both heads interleaved, barrier-free ----------------
  f32x4 pacc[2][4][2];
  char* Pb0 = slice;
  char* Pb1 = slice + 8192;
  {
    const f32x4 z4 = {0.f, 0.f, 0.f, 0.f};
    f32x4 dacc[2][4][4];
    __builtin_amdgcn_s_setprio(1);
#pragma unroll
    for (int hh = 0; hh < 2; ++hh)
#pragma unroll
      for (int mt = 0; mt < 4; ++mt)
#pragma unroll
        for (int nt = 0; nt < 4; ++nt)
          dacc[hh][mt][nt] = __builtin_amdgcn_mfma_f32_16x16x32_bf16(qf[hh][mt], kf[hh][nt], z4, 0, 0, 0);
    __builtin_amdgcn_s_setprio(0);

    const int h0 = wave * 2;
    // softmax WITHOUT max-subtraction (scores are O(1) here; exp overflow-safe;
    // mathematically identical to the reference)
#pragma unroll
    for (int mt = 0; mt < 4; ++mt) {
#pragma unroll
      for (int r = 0; r < 4; ++r) {
        const int i = mt * 16 + g4 * 4 + r;
        float p0[4], p1[4], s0 = 0.f, s1 = 0.f;
#pragma unroll
        for (int nt = 0; nt < 4; ++nt) {
          const int j = nt * 16 + c16;
          float v0 = dacc[0][mt][nt][r] * SCALE_F;
          float v1 = dacc[1][mt][nt][r] * SCALE_F;
          if (j < NPOS) {
            if (i < NPOS) { const float bb = bias_s[i * 49 + j]; v0 += bb; v1 += bb; }
          } else {
            v0 = -1e30f; v1 = -1e30f;
          }
          p0[nt] = __expf(v0); s0 += p0[nt];
          p1[nt] = __expf(v1); s1 += p1[nt];
        }
        s0 += __shfl_xor(s0, 1); s1 += __shfl_xor(s1, 1);
        s0 += __shfl_xor(s0, 2); s1 += __shfl_xor(s1, 2);
        s0 += __shfl_xor(s0, 4); s1 += __shfl_xor(s1, 4);
        s0 += __shfl_xor(s0, 8); s1 += __shfl_xor(s1, 8);
        const float inv0 = 1.f / s0, inv1 = 1.f / s1;
        if (i < NPOS) {
          float* ap0 = attng + ((size_t)(work * NHEADS + h0) * 49 + i) * 49;
          float* ap1 = ap0 + 49 * 49;
#pragma unroll
          for (int nt = 0; nt < 4; ++nt) {
            const int j = nt * 16 + c16;
            if (j < NPOS) { ap0[j] = p0[nt] * inv0; ap1[j] = p1[nt] * inv1; }
          }
        }
#pragma unroll
        for (int nt = 0; nt < 4; ++nt) {
          const int j = nt * 16 + c16;
          *(__bf16*)(Pb0 + i * 128 + 16 * ((j >> 3) ^ (i & 7)) + 2 * (j & 7)) = (__bf16)(p0[nt] * inv0);
          *(__bf16*)(Pb1 + i * 128 + 16 * ((j >> 3) ^ (i & 7)) + 2 * (j & 7)) = (__bf16)(p1[nt] * inv1);
        }
      }
    }

    // PV
    __builtin_amdgcn_s_setprio(1);
#pragma unroll
    for (int hh = 0; hh < 2; ++hh) {
      char* Pb = hh ? Pb1 : Pb0;
#pragma unroll
      for (int mt = 0; mt < 4; ++mt) {
        const int i = mt * 16 + c16;
        bf16x8 pa0 = *(const bf16x8*)(Pb + i * 128 + 16 * ((0 + g4) ^ (i & 7)));
        bf16x8 pa1 = *(const bf16x8*)(Pb + i * 128 + 16 * ((4 + g4) ^ (i & 7)));
#pragma unroll
        for (int nt = 0; nt < 2; ++nt) {
          f32x4 acc = {0.f, 0.f, 0.f, 0.f};
          acc = __builtin_amdgcn_mfma_f32_16x16x32_bf16(pa0, vf[hh][nt][0], acc, 0, 0, 0);
          acc = __builtin_amdgcn_mfma_f32_16x16x32_bf16(pa1, vf[hh][nt][1], acc, 0, 0, 0);
          pacc[hh][mt][nt] = acc;
        }
      }
    }
    __builtin_amdgcn_s_setprio(0);
  }

  if constexpr (MODE == 1) {
    // ---------------- store attn_out (pre-Wo) -> aoT_g[win][49][256] bf16 ----------------
    __bf16* ag = aoT_g + (size_t)work * 12544;
#pragma unroll
    for (int hh = 0; hh < 2; ++hh) {
      const int h = wave * 2 + hh;
#pragma unroll
      for (int mt = 0; mt < 4; ++mt)
#pragma unroll
        for (int e = 0; e < 4; ++e) {
          const int pos = mt * 16 + g4 * 4 + e;
          if (pos < NPOS) {
            ag[pos * 256 + h * 32 + c16]      = (__bf16)pacc[hh][mt][0][e];
            ag[pos * 256 + h * 32 + 16 + c16] = (__bf16)pacc[hh][mt][1][e];
          }
        }
    }
  } else {
    __syncthreads();  // all waves done with slices; reuse smem[0..33792) as aoT
#pragma unroll
    for (int hh = 0; hh < 2; ++hh) {
      const int h = wave * 2 + hh;
#pragma unroll
      for (int mt = 0; mt < 4; ++mt)
#pragma unroll
        for (int nt = 0; nt < 2; ++nt)
#pragma unroll
          for (int e = 0; e < 4; ++e) {
            const int i = mt * 16 + g4 * 4 + e;
            const int cc = h * 32 + nt * 16 + c16;
            aoT[i * AOT_PITCH + cc] = (__bf16)pacc[hh][mt][nt][e];
          }
    }
    __syncthreads();
    {
      bf16x8 Cf0[16], Cf1[16];
      const __bf16* Bp = aoT + l31 * AOT_PITCH + g2 * 8;
#pragma unroll
      for (int ks = 0; ks < 16; ++ks) {
        Cf0[ks] = *(const bf16x8*)(Bp + ks * 16);
        Cf1[ks] = *(const bf16x8*)(Bp + 32 * AOT_PITCH + ks * 16);
      }
      const __bf16* Ap0 = wo + (size_t)(wave * 64 + l31) * 256 + g2 * 8;
      const __bf16* Ap1 = Ap0 + 32 * 256;
      f32x16 a00 = zero16(), a01 = zero16(), a10 = zero16(), a11 = zero16();
      __builtin_amdgcn_s_setprio(1);
#pragma unroll
      for (int ks = 0; ks < 16; ++ks) {
        bf16x8 A0 = *(const bf16x8*)(Ap0 + ks * 16);
        bf16x8 A1 = *(const bf16x8*)(Ap1 + ks * 16);
        a00 = __builtin_amdgcn_mfma_f32_32x32x16_bf16(A0, Cf0[ks], a00, 0, 0, 0);
        a01 = __builtin_amdgcn_mfma_f32_32x32x16_bf16(A0, Cf1[ks], a01, 0, 0, 0);
        a10 = __builtin_amdgcn_mfma_f32_32x32x16_bf16(A1, Cf0[ks], a10, 0, 0, 0);
        a11 = __builtin_amdgcn_mfma_f32_32x32x16_bf16(A1, Cf1[ks], a11, 0, 0, 0);
      }
      __builtin_amdgcn_s_setprio(0);
      float* og = outg + (size_t)b * 256 * 12544;
#define STORE_OUT(ACC, MT, NT)                                                    \
      {                                                                           \
        const int n_ = (NT) * 32 + l31;                                           \
        if (n_ < NPOS) {                                                          \
          const int pr_ = n_ / 7, pc_ = n_ - pr_ * 7;                             \
          float* orow = og + (size_t)(r0 + pr_) * 112 + (c0 + pc_);               \
          _Pragma("unroll") for (int rg = 0; rg < 16; ++rg) {                     \
            const int o2 = wave * 64 + (MT) * 32 + (rg & 3) + 8 * (rg >> 2) + 4 * g2; \
            orow[(size_t)o2 * 12544] = ACC[rg] + bo_s[o2];                        \
          }                                                                       \
        }                                                                         \
      }
      STORE_OUT(a00, 0, 0)
      STORE_OUT(a01, 0, 1)
      STORE_OUT(a10, 1, 0)
      STORE_OUT(a11, 1, 1)
    }
  }
}

// ---------------- kernel B: out[b][oc][i1*7+pr][0..111] = Wo @ attn_out + bo ----------------
__global__ __launch_bounds__(256, 2) void oproj_kernel(
    const __bf16* __restrict__ aoT_g, const __bf16* __restrict__ wo,
    const float* __restrict__ bo_g, float* __restrict__ outg) {
  __shared__ __bf16 aoB[112 * 264];
  __shared__ float bo_s[256];
  const int tid = threadIdx.x;
  const int bid = blockIdx.x;
  const int work = (bid & 7) * 224 + (bid >> 3);  // 1792 = 8*224, bijective
  const int pr = work % 7;
  const int g  = work / 7;
  const int i1 = g & 15, b = g >> 4;
  const int wave = tid >> 6, lane = tid & 63;
  const int c16 = lane & 15, g4 = lane >> 4;

  // stage 112 rows (i2,pc) -> aoB[col = i2*7+pc][ic 0..255] (pitch 264 elems)
  {
    const int rr = tid >> 5, coff = (tid & 31) * 8;
#pragma unroll
    for (int it = 0; it < 14; ++it) {
      const int gr = it * 8 + rr;          // 0..111 == col index
      const int i2 = gr / 7, pc = gr - i2 * 7;
      const size_t src = ((size_t)((b * 256 + i1 * 16 + i2) * 49 + pr * 7 + pc)) * 256 + coff;
      *(bf16x8*)(aoB + gr * 264 + coff) = *(const bf16x8*)(aoT_g + src);
    }
    bo_s[tid] = bo_g[tid];
  }
  __syncthreads();

  const int oc0 = wave * 64;
  f32x4 acc[4][7];
#pragma unroll
  for (int mt = 0; mt < 4; ++mt)
#pragma unroll
    for (int nt = 0; nt < 7; ++nt) acc[mt][nt] = f32x4{0.f, 0.f, 0.f, 0.f};
#pragma unroll
  for (int kk = 0; kk < 8; ++kk) {
    bf16x8 Af[4], Bf[7];
#pragma unroll
    for (int mt = 0; mt < 4; ++mt)
      Af[mt] = *(const bf16x8*)(wo + (size_t)(oc0 + mt * 16 + c16) * 256 + kk * 32 + g4 * 8);
#pragma unroll
    for (int nt = 0; nt < 7; ++nt)
      Bf[nt] = *(const bf16x8*)(aoB + (nt * 16 + c16) * 264 + kk * 32 + g4 * 8);
    __builtin_amdgcn_s_setprio(1);
#pragma unroll
    for (int mt = 0; mt < 4; ++mt)
#pragma unroll
      for (int nt = 0; nt < 7; ++nt)
        acc[mt][nt] = __builtin_amdgcn_mfma_f32_16x16x32_bf16(Af[mt], Bf[nt], acc[mt][nt], 0, 0, 0);
    __builtin_amdgcn_s_setprio(0);
  }
  float* orow = outg + (size_t)b * 256 * 12544 + (size_t)(i1 * 7 + pr) * 112;
#pragma unroll
  for (int mt = 0; mt < 4; ++mt)
#pragma unroll
    for (int e = 0; e < 4; ++e) {
      const int oc = oc0 + mt * 16 + g4 * 4 + e;
      const float bb = bo_s[oc];
#pragma unroll
      for (int nt = 0; nt < 7; ++nt)
        orow[(size_t)oc * 12544 + nt * 16 + c16] = acc[mt][nt][e] + bb;
    }
}

extern "C" void kernel_launch(void* const* d_in, const int* in_sizes, int n_in,
                              void* d_out, int out_size, void* d_ws, size_t ws_size,
                              hipStream_t stream) {
  const float* x   = (const float*)d_in[0];
  const float* Wq  = (const float*)d_in[1];
  const float* Wkv = (const float*)d_in[2];
  const float* Wo  = (const float*)d_in[3];
  const float* bo  = (const float*)d_in[4];
  const float* pos = (const float*)d_in[5];
  const int*   rel = (const int*)d_in[6];

  float* outg  = (float*)d_out;
  float* attng = outg + (size_t)16 * 256 * 112 * 112;

  __bf16* wqkv = (__bf16*)d_ws;
  __bf16* wo   = wqkv + 768 * 256;
  float*  bias = (float*)(wo + 256 * 256);

  size_t base = 768 * 256 * 2 + 256 * 256 * 2 + 2401 * 4;
  base = (base + 255) & ~(size_t)255;
  const size_t ao_bytes = (size_t)4096 * 12544 * 2;
  const bool split = (ws_size >= base + ao_bytes);
  __bf16* aoT_g = (__bf16*)((char*)d_ws + base);

  hipFuncSetAttribute((const void*)attn_kernel<0>,
                      hipFuncAttributeMaxDynamicSharedMemorySize, LDS_BYTES);
  hipFuncSetAttribute((const void*)attn_kernel<1>,
                      hipFuncAttributeMaxDynamicSharedMemorySize, LDS_BYTES);

  prep_kernel<<<dim3(512), dim3(256), 0, stream>>>(Wq, Wkv, Wo, pos, rel, wqkv, wo, bias);
  if (split) {
    attn_kernel<1><<<dim3(4096), dim3(256), LDS_BYTES, stream>>>(
        x, wqkv, wo, bias, bo, outg, attng, aoT_g);
    oproj_kernel<<<dim3(1792), dim3(256), 0, stream>>>(aoT_g, wo, bo, outg);
  } else {
    attn_kernel<0><<<dim3(4096), dim3(256), LDS_BYTES, stream>>>(
        x, wqkv, wo, bias, bo, outg, attng, nullptr);
  }
}